// Round 14
// baseline (596.542 us; speedup 1.0000x reference)
//
#include <hip/hip_runtime.h>
#include <math.h>

#define NTOT   131072
#define NPG    256
#define BGR    512
#define HID    128
#define EDG    2097152
#define EPG    4096       // edges per graph (contiguous slice [g*4096,(g+1)*4096))
#define EPGP   4864       // padded CSR capacity: 4096 + 3*256
#define KTOP   60
#define TLDIM  385

// X (gather) layout: float4 c4 -> phys within 32-float4 row
__device__ __forceinline__ int physX(int row, int c4) {
    return (c4 + row + (row >> 3)) & 31;
}
// AGG (GEMM) layout
__device__ __forceinline__ int physA(int row, int c4) {
    return (c4 + (row >> 3) + ((row & 1) << 2)) & 31;
}

// ============ mega kernel: build + embed + 3 GCN layers + key + top-60 + P2 export ============
__global__ __launch_bounds__(1024, 4) void k_gnn(
        const float* __restrict__ zt, const int* __restrict__ z,
        const int* __restrict__ ei, const float* __restrict__ ew,
        const float* __restrict__ W0, const float* __restrict__ b0,
        const float* __restrict__ W1, const float* __restrict__ b1,
        const float* __restrict__ W2, const float* __restrict__ b2,
        const float* __restrict__ W3, const float* __restrict__ b3,
        float* __restrict__ X0, float* __restrict__ X1,
        float* __restrict__ P2, float* __restrict__ selK, int* __restrict__ selI) {
    __shared__ float4 XS[NPG * 32];              // 128 KB; build scratch first, then X/AGG/X2
    __shared__ __align__(16) float wnL[EPGP];    // normalized edge weights (padded CSR)
    __shared__ __align__(4) unsigned char esrcL[EPGP];
    __shared__ unsigned short offL[NPG + 2];
    __shared__ unsigned short mLn[NPG];
    __shared__ int    cntL[NPG];
    __shared__ float  selfnL[NPG];
    __shared__ float  dinvL[NPG];
    __shared__ float  t3s[NPG];
    __shared__ float  keyL[NPG];
    __shared__ int    selN[KTOP];

    int t = threadIdx.x;
    int g = blockIdx.x;

    // ---- build scratch aliases inside XS (dead once XS staged) ----
    float*          ewL  = (float*)XS;                               // [0,16K)
    unsigned char*  srcB = (unsigned char*)XS + 16384;               // [16K,20K)
    unsigned char*  dstB = (unsigned char*)XS + 20480;               // [20K,24K)
    unsigned int*   hh   = (unsigned int*)((char*)XS + 24576);       // 64 x 257 u32

    for (int j = t; j < EPG; j += 1024) {
        int e = g * EPG + j;
        ewL[j]  = ew[e];
        srcB[j] = (unsigned char)(ei[e] & (NPG - 1));
        dstB[j] = (unsigned char)(ei[EDG + e] & (NPG - 1));
    }
    for (int i = t; i < 64 * 257; i += 1024) hh[i] = 0;
    __syncthreads();
    if (t < 64) {                                 // pass A: per-chunk dst histogram
        int base = t * 64;
        unsigned int* hr = hh + t * 257;
        for (int i = 0; i < 64; i++) hr[dstB[base + i]]++;
    }
    __syncthreads();
    if (t < NPG) {                                // totals per dst
        int tot = 0;
        for (int c = 0; c < 64; c++) tot += hh[c * 257 + t];
        mLn[t]  = (unsigned short)tot;
        cntL[t] = (tot + 3) & ~3;
    }
    __syncthreads();
    if (t < 64) {                                 // exclusive scan, wave 0, shfl
        int carry = 0;
        if (t == 0) offL[0] = 0;
        for (int seg = 0; seg < 4; seg++) {
            int v = cntL[seg * 64 + t];
#pragma unroll
            for (int d = 1; d < 64; d <<= 1) {
                int u = __shfl_up(v, d);
                if (t >= d) v += u;
            }
            offL[seg * 64 + t + 1] = (unsigned short)(v + carry);
            carry += __shfl(v, 63);
        }
    }
    __syncthreads();
    if (t < NPG) {                                // cursors
        int run = offL[t];
        for (int c = 0; c < 64; c++) {
            int tmp = hh[c * 257 + t];
            hh[c * 257 + t] = (unsigned int)run;
            run += tmp;
        }
    }
    __syncthreads();
    if (t < 64) {                                 // pass B: stable placement (e-ascending/dst)
        int base = t * 64;
        unsigned int* hr = hh + t * 257;
        for (int i = 0; i < 64; i++) {
            int e = base + i;
            int d = dstB[e];
            int slot = hr[d];
            hr[d] = slot + 1;
            esrcL[slot] = srcB[e];
            wnL[slot]   = ewL[e];
        }
    }
    __syncthreads();
    if (t < NPG) {                                // deg -> dinv (self-loop last)
        int o = offL[t], m = mLn[t];
        float s = 0.f;
        for (int i = 0; i < m; i++) s += wnL[o + i];
        float dv = 1.0f / sqrtf(s + 1.0f);
        dinvL[t]  = dv;
        selfnL[t] = dv * dv;
    }
    __syncthreads();
    if (t < NPG) {                                // normalize + exact no-op padding
        int o = offL[t], m = mLn[t], pc = cntL[t];
        float dn = dinvL[t];
        for (int i = 0; i < m; i++)
            wnL[o + i] = dinvL[esrcL[o + i]] * wnL[o + i] * dn;
        for (int i = m; i < pc; i++) {
            esrcL[o + i] = (unsigned char)t;
            wnL[o + i]   = 0.f;
        }
    }
    __syncthreads();
    for (int i = t; i < NPG * 32; i += 1024) {    // stage X = zt[z[n]]
        int row = i >> 5, c4 = i & 31;
        int zi = z[g * NPG + row];
        XS[row * 32 + physX(row, c4)] = ((const float4*)zt)[(size_t)zi * 32 + c4];
    }
    __syncthreads();

    const unsigned int* esrcW = (const unsigned int*)esrcL;
    const float4*       wn4   = (const float4*)wnL;
    int wid  = t >> 6;
    int l    = t & 63;
    int half = l >> 5;
    int c4   = l & 31;
    // GEMM mapping: lane = 4 rows (rowL), wave = 8 cols (colW) -> broadcast W loads,
    // A-read bank = (k4 + l>>1) & 31 -> exactly 2 lanes/bank (free, m136)
    int rowL = t & 63;
    int colW = t >> 6;
    int cq0 = colW * 2, cq1 = cq0 + 1;

    // ================= 3 GCN layers =================
#pragma unroll 1
    for (int layer = 0; layer < 3; layer++) {
        const float* W    = (layer == 0) ? W0 : (layer == 1) ? W1 : W2;
        const float* bias = (layer == 0) ? b0 : (layer == 1) ? b1 : b2;
        float* Xout       = (layer == 0) ? X0 : (layer == 1) ? X1 : nullptr;

        // ---- gather: half-wave per node, row-broadcast reads, 2-deep pipeline ----
        float4 accA[8];
#pragma unroll 1
        for (int it = 0; it < 8; it++) {
            int p    = wid * 8 + it;
            int node = 2 * p + half;
            int oA = offL[2 * p], oM = offL[2 * p + 1], oE = offL[2 * p + 2];
            int m4A = (oM - oA) >> 2, m4B = (oE - oM) >> 2;
            int mmax4 = m4A > m4B ? m4A : m4B;
            int o4 = (half ? oM : oA) >> 2;
            int m4 = half ? m4B : m4A;
            unsigned int selfpack = (unsigned int)node * 0x01010101u;
            float4 acc = make_float4(0.f, 0.f, 0.f, 0.f);

            unsigned int s_cur = selfpack, s_nxt = selfpack;
            float4 w_cur = make_float4(0.f, 0.f, 0.f, 0.f);
            float4 w_nxt = make_float4(0.f, 0.f, 0.f, 0.f);
            float4 v0, v1, v2, v3;
            if (mmax4 > 0) {
                {
                    int idx = o4;
                    unsigned int ss = esrcW[idx]; float4 ww = wn4[idx];
                    if (0 >= m4) { ss = selfpack; ww = make_float4(0.f,0.f,0.f,0.f); }
                    s_cur = ss; w_cur = ww;
                }
                {
                    int jc = (1 < m4) ? 1 : (m4 > 0 ? m4 - 1 : 0);
                    int idx = o4 + jc;
                    unsigned int ss = esrcW[idx]; float4 ww = wn4[idx];
                    if (1 >= m4) { ss = selfpack; ww = make_float4(0.f,0.f,0.f,0.f); }
                    s_nxt = ss; w_nxt = ww;
                }
                int a0 =  s_cur        & 255, a1 = (s_cur >> 8)  & 255;
                int a2i = (s_cur >> 16) & 255, a3 = (s_cur >> 24) & 255;
                v0 = XS[a0 * 32 + physX(a0, c4)];
                v1 = XS[a1 * 32 + physX(a1, c4)];
                v2 = XS[a2i * 32 + physX(a2i, c4)];
                v3 = XS[a3 * 32 + physX(a3, c4)];
            }
            for (int j4 = 0; j4 < mmax4; j4++) {
                int b0i =  s_nxt        & 255, b1i = (s_nxt >> 8)  & 255;
                int b2i = (s_nxt >> 16) & 255, b3i = (s_nxt >> 24) & 255;
                float4 n0 = XS[b0i * 32 + physX(b0i, c4)];
                float4 n1 = XS[b1i * 32 + physX(b1i, c4)];
                float4 n2 = XS[b2i * 32 + physX(b2i, c4)];
                float4 n3 = XS[b3i * 32 + physX(b3i, c4)];
                int jn = j4 + 2;
                int jc = (jn < m4) ? jn : (m4 > 0 ? m4 - 1 : 0);
                int idx = o4 + jc;
                unsigned int s2_ = esrcW[idx];
                float4 w2_ = wn4[idx];
                if (jn >= m4) { s2_ = selfpack; w2_ = make_float4(0.f,0.f,0.f,0.f); }
                acc.x += w_cur.x * v0.x; acc.y += w_cur.x * v0.y;
                acc.z += w_cur.x * v0.z; acc.w += w_cur.x * v0.w;
                acc.x += w_cur.y * v1.x; acc.y += w_cur.y * v1.y;
                acc.z += w_cur.y * v1.z; acc.w += w_cur.y * v1.w;
                acc.x += w_cur.z * v2.x; acc.y += w_cur.z * v2.y;
                acc.z += w_cur.z * v2.z; acc.w += w_cur.z * v2.w;
                acc.x += w_cur.w * v3.x; acc.y += w_cur.w * v3.y;
                acc.z += w_cur.w * v3.z; acc.w += w_cur.w * v3.w;
                v0 = n0; v1 = n1; v2 = n2; v3 = n3;
                w_cur = w_nxt; s_nxt = s2_; w_nxt = w2_;
            }
            float wsf = selfnL[node];             // self-loop LAST
            float4 sv = XS[node * 32 + physX(node, c4)];
            acc.x += wsf * sv.x; acc.y += wsf * sv.y;
            acc.z += wsf * sv.z; acc.w += wsf * sv.w;
            accA[it] = acc;
        }
        __syncthreads();
#pragma unroll
        for (int it = 0; it < 8; it++) {
            int node = 2 * (wid * 8 + it) + half;
            XS[node * 32 + physA(node, c4)] = accA[it];
        }
        __syncthreads();

        // ---- GEMM 256x128 @ 128x128: lane = 4 rows, wave = 8 cols ----
        float a2[4][8];
#pragma unroll
        for (int i = 0; i < 4; i++)
#pragma unroll
            for (int j = 0; j < 8; j++) a2[i][j] = 0.f;
        for (int k4 = 0; k4 < 32; k4++) {
            float4 a4[4];
#pragma unroll
            for (int i = 0; i < 4; i++) {
                int rl = rowL * 4 + i;
                a4[i] = XS[rl * 32 + physA(rl, k4)];
            }
#pragma unroll
            for (int kw = 0; kw < 4; kw++) {      // k strictly ascending (exact)
                const float4* wp = (const float4*)(W + (size_t)(k4 * 4 + kw) * HID);
                float4 wv0 = wp[cq0];             // wave-uniform -> broadcast
                float4 wv1 = wp[cq1];
#pragma unroll
                for (int i = 0; i < 4; i++) {
                    float a = (kw == 0) ? a4[i].x : (kw == 1) ? a4[i].y
                            : (kw == 2) ? a4[i].z : a4[i].w;
                    a2[i][0] += a * wv0.x; a2[i][1] += a * wv0.y;
                    a2[i][2] += a * wv0.z; a2[i][3] += a * wv0.w;
                    a2[i][4] += a * wv1.x; a2[i][5] += a * wv1.y;
                    a2[i][6] += a * wv1.z; a2[i][7] += a * wv1.w;
                }
            }
        }
        float4 bv0 = ((const float4*)bias)[cq0];
        float4 bv1 = ((const float4*)bias)[cq1];
        float4 o0[4], o1[4];
#pragma unroll
        for (int i = 0; i < 4; i++) {
            o0[i].x = tanhf(a2[i][0] + bv0.x); o0[i].y = tanhf(a2[i][1] + bv0.y);
            o0[i].z = tanhf(a2[i][2] + bv0.z); o0[i].w = tanhf(a2[i][3] + bv0.w);
            o1[i].x = tanhf(a2[i][4] + bv1.x); o1[i].y = tanhf(a2[i][5] + bv1.y);
            o1[i].z = tanhf(a2[i][6] + bv1.z); o1[i].w = tanhf(a2[i][7] + bv1.w);
        }
        __syncthreads();
#pragma unroll
        for (int i = 0; i < 4; i++) {
            int rl = rowL * 4 + i;
            XS[rl * 32 + physX(rl, cq0)] = o0[i];
            XS[rl * 32 + physX(rl, cq1)] = o1[i];
        }
        __syncthreads();
        if (Xout) {                               // coalesced copy-out (X0/X1 only)
            float4* dst = (float4*)Xout + (size_t)g * NPG * 32;
            for (int i = t; i < NPG * 32; i += 1024) {
                int row = i >> 5, cc = i & 31;
                dst[i] = XS[row * 32 + physX(row, cc)];
            }
        }
    }

    // ---- layer 3 scalar: t3 = X2-row . W3 (exact 4-part structure) ----
    {
        int n = t >> 2, part = t & 3;
        const float4* w4 = (const float4*)W3;
        const float4* rb = XS + n * 32;
        float s = 0.f;
#pragma unroll
        for (int q = 0; q < 8; q++) {
            float4 v = rb[physX(n, part * 8 + q)];
            float4 ww = w4[part * 8 + q];
            s += v.x * ww.x + v.y * ww.y + v.z * ww.z + v.w * ww.w;
        }
        s += __shfl_down(s, 2, 4);
        s += __shfl_down(s, 1, 4);
        if (part == 0) t3s[n] = s;
    }
    __syncthreads();

    // ---- key + stable top-60 rank ----
    if (t < NPG) {
        int o = offL[t], m2 = mLn[t];
        float s = 0.f;
        for (int i = 0; i < m2; i++)
            s += wnL[o + i] * t3s[esrcL[o + i]];
        s += selfnL[t] * t3s[t];
        keyL[t] = tanhf(s + b3[0]);
    }
    __syncthreads();
    if (t < NPG) {
        float ki = keyL[t];
        int rank = 0;
        for (int j = 0; j < NPG; j++) {
            float kj = keyL[j];
            rank += (kj > ki) || (kj == ki && j < t);
        }
        if (rank < KTOP) selN[rank] = t;
    }
    __syncthreads();
    // ---- export: pooled X2 rows (contiguous), selected keys, selected ids ----
    if (t < KTOP) {
        int nd = selN[t];
        selI[g * KTOP + t] = nd;
        selK[g * KTOP + t] = keyL[nd];
    }
    for (int i = t; i < KTOP * 32; i += 1024) {
        int r = i >> 5, q = i & 31;
        int nd = selN[r];
        ((float4*)P2)[(size_t)g * KTOP * 32 + i] = XS[nd * 32 + physX(nd, q)];
    }
}

// ---------------- conv/MLP head: one 256-thread block per graph (r12-proven) ----------------
__global__ __launch_bounds__(256) void k_head(const float* __restrict__ X0,
                                              const float* __restrict__ X1,
                                              const float* __restrict__ P2,
                                              const float* __restrict__ selK,
                                              const int* __restrict__ selI,
                                              const float* __restrict__ c1w,
                                              const float* __restrict__ c1b,
                                              const float* __restrict__ c2w,
                                              const float* __restrict__ c2b,
                                              const float* __restrict__ l1w,
                                              const float* __restrict__ l1b,
                                              const float* __restrict__ l2w,
                                              const float* __restrict__ l2b,
                                              float* __restrict__ out) {
    __shared__ __align__(16) float pch[KTOP * 132];
    __shared__ __align__(16) float w1s[16 * 132];
    __shared__ int   seln[KTOP];
    __shared__ float selk[KTOP];
    __shared__ float c1s[16 * KTOP];
    __shared__ float mps[16 * 30];
    __shared__ float w2s[32 * 80];
    __shared__ float yb[832];
    __shared__ float l1p[256];
    __shared__ float l1v[128];

    int g = blockIdx.x, t = threadIdx.x;
    if (t < KTOP) {
        seln[t] = selI[g * KTOP + t];
        selk[t] = selK[g * KTOP + t];
    }

    float acc1[4] = {0.f, 0.f, 0.f, 0.f};
    for (int tc = 0; tc < 3; tc++) {
        const float* Xsrc = (tc == 0) ? X0 : X1;
        __syncthreads();
        for (int i = t; i < KTOP * 32; i += 256) {
            int k = i >> 5, q = i & 31;
            float4 v;
            if (tc < 2) {
                int nd = seln[k];
                v = ((const float4*)Xsrc)[((size_t)g * NPG + nd) * 32 + q];
            } else {
                v = ((const float4*)P2)[(size_t)g * KTOP * 32 + i];   // contiguous
            }
            *((float4*)&pch[k * 132 + q * 4]) = v;
        }
        for (int i = t; i < 16 * 128; i += 256) {
            int ch = i >> 7, tt = i & 127;
            w1s[ch * 132 + tt] = c1w[ch * TLDIM + tc * 128 + tt];
        }
        __syncthreads();
#pragma unroll
        for (int it = 0; it < 4; it++) {
            int e = it * 256 + t;
            if (e < 960) {                        // e = k*16 + ch
                int k = e >> 4, ch = e & 15;
                const float* pr = &pch[k * 132];
                const float* wr = &w1s[ch * 132];
                float s = 0.f;
#pragma unroll
                for (int q = 0; q < 32; q++) {
                    float4 pv = *((float4*)&pr[q * 4]);
                    float4 wv = *((float4*)&wr[q * 4]);
                    s += pv.x * wv.x + pv.y * wv.y + pv.z * wv.z + pv.w * wv.w;
                }
                acc1[it] += s;
            }
        }
    }
    __syncthreads();
#pragma unroll
    for (int it = 0; it < 4; it++) {
        int e = it * 256 + t;
        if (e < 960) {
            int k = e >> 4, ch = e & 15;
            float v = acc1[it] + selk[k] * c1w[ch * TLDIM + 384] + c1b[ch];
            c1s[ch * KTOP + k] = fmaxf(v, 0.f);
        }
    }
    for (int i = t; i < 2560; i += 256) w2s[i] = c2w[i];
    __syncthreads();
    for (int i = t; i < 480; i += 256) {
        int ch = i / 30, p = i - ch * 30;
        mps[ch * 30 + p] = fmaxf(c1s[ch * KTOP + 2 * p], c1s[ch * KTOP + 2 * p + 1]);
    }
    __syncthreads();
    for (int e = t; e < 832; e += 256) {
        int oc = e / 26, q = e - oc * 26;
        float s = 0.f;
#pragma unroll
        for (int ic = 0; ic < 16; ic++) {
            const float* mr = &mps[ic * 30 + q];
            const float* wr = &w2s[oc * 80 + ic * 5];
#pragma unroll
            for (int j = 0; j < 5; j++) s += mr[j] * wr[j];
        }
        yb[e] = fmaxf(s + c2b[oc], 0.f);
    }
    __syncthreads();
    {
        int u = t & 127, h = t >> 7;
        float s = 0.f;
        for (int d = h * 416; d < h * 416 + 416; d++) s += yb[d] * l1w[d * 128 + u];
        l1p[t] = s;
    }
    __syncthreads();
    if (t < 128) {
        float v = fmaxf(l1p[t] + l1p[t + 128] + l1b[t], 0.f);
        l1v[t] = v * l2w[t];
    }
    __syncthreads();
    if (t < 64) {
        float v = l1v[t] + l1v[t + 64];
        v += __shfl_down(v, 32);
        v += __shfl_down(v, 16);
        v += __shfl_down(v, 8);
        v += __shfl_down(v, 4);
        v += __shfl_down(v, 2);
        v += __shfl_down(v, 1);
        if (t == 0) out[g] = v + l2b[0];
    }
}

extern "C" void kernel_launch(void* const* d_in, const int* in_sizes, int n_in,
                              void* d_out, int out_size, void* d_ws, size_t ws_size,
                              hipStream_t stream) {
    (void)in_sizes; (void)n_in; (void)out_size; (void)ws_size;
    const float* zt  = (const float*)d_in[0];
    const float* W0  = (const float*)d_in[1];
    const float* b0  = (const float*)d_in[2];
    const float* W1  = (const float*)d_in[3];
    const float* b1  = (const float*)d_in[4];
    const float* W2  = (const float*)d_in[5];
    const float* b2  = (const float*)d_in[6];
    const float* W3  = (const float*)d_in[7];
    const float* b3  = (const float*)d_in[8];
    const float* c1w = (const float*)d_in[9];
    const float* c1b = (const float*)d_in[10];
    const float* c2w = (const float*)d_in[11];
    const float* c2b = (const float*)d_in[12];
    const float* l1w = (const float*)d_in[13];
    const float* l1b = (const float*)d_in[14];
    const float* l2w = (const float*)d_in[15];
    const float* l2b = (const float*)d_in[16];
    const float* ew  = (const float*)d_in[17];
    const int*   z   = (const int*)d_in[18];
    const int*   ei  = (const int*)d_in[19];
    float* out = (float*)d_out;

    char* wsp = (char*)d_ws;
    size_t off = 0;
    auto alloc = [&](size_t bytes) -> void* {
        void* p = wsp + off;
        off += (bytes + 255) & ~(size_t)255;
        return p;
    };
    float* X0   = (float*)alloc((size_t)NTOT * HID * 4);
    float* X1   = (float*)alloc((size_t)NTOT * HID * 4);
    float* P2   = (float*)alloc((size_t)BGR * KTOP * HID * 4);
    float* selK = (float*)alloc((size_t)BGR * KTOP * 4);
    int*   selI = (int*)  alloc((size_t)BGR * KTOP * 4);

    k_gnn <<<BGR, dim3(1024), 0, stream>>>(zt, z, ei, ew,
                                           W0, b0, W1, b1, W2, b2, W3, b3,
                                           X0, X1, P2, selK, selI);
    k_head<<<BGR, dim3(256), 0, stream>>>(X0, X1, P2, selK, selI,
                                          c1w, c1b, c2w, c2b,
                                          l1w, l1b, l2w, l2b, out);
}

// Round 15
// 551.507 us; speedup vs baseline: 1.0817x; 1.0817x over previous
//
#include <hip/hip_runtime.h>
#include <math.h>

#define NTOT   131072
#define NPG    256
#define BGR    512
#define HID    128
#define EDG    2097152
#define EPG    4096       // edges per graph (contiguous slice [g*4096,(g+1)*4096))
#define EPGP   4864       // padded CSR capacity: 4096 + 3*256
#define KTOP   60
#define TLDIM  385

// X (gather) layout: float4 c4 -> phys within 32-float4 row
__device__ __forceinline__ int physX(int row, int c4) {
    return (c4 + row + (row >> 3)) & 31;
}
// AGG (GEMM) layout (r8/r12-verified conflict-free with rg=t&31 mapping)
__device__ __forceinline__ int physA(int row, int c4) {
    return (c4 + (row >> 3) + ((row & 1) << 2)) & 31;
}

// ============ mega kernel: build + embed + 3 GCN layers + key + top-60 + P2 export ============
__global__ __launch_bounds__(1024, 4) void k_gnn(
        const float* __restrict__ zt, const int* __restrict__ z,
        const int* __restrict__ ei, const float* __restrict__ ew,
        const float* __restrict__ W0, const float* __restrict__ b0,
        const float* __restrict__ W1, const float* __restrict__ b1,
        const float* __restrict__ W2, const float* __restrict__ b2,
        const float* __restrict__ W3, const float* __restrict__ b3,
        float* __restrict__ X0, float* __restrict__ X1,
        float* __restrict__ P2, float* __restrict__ selK, int* __restrict__ selI) {
    __shared__ float4 XS[NPG * 32];              // 128 KB; build scratch first, then X/AGG/X2
    __shared__ __align__(16) float wnL[EPGP];    // normalized edge weights (padded CSR)
    __shared__ __align__(4) unsigned char esrcL[EPGP];
    __shared__ unsigned short offL[NPG + 2];
    __shared__ unsigned short mLn[NPG];
    __shared__ int    cntL[NPG];
    __shared__ float  selfnL[NPG];
    __shared__ float  dinvL[NPG];
    __shared__ float  t3s[NPG];
    __shared__ float  keyL[NPG];
    __shared__ int    selN[KTOP];

    int t = threadIdx.x;
    int g = blockIdx.x;

    // ---- build scratch aliases inside XS (dead once XS staged) ----
    float*          ewL  = (float*)XS;                               // [0,16K)
    unsigned char*  srcB = (unsigned char*)XS + 16384;               // [16K,20K)
    unsigned char*  dstB = (unsigned char*)XS + 20480;               // [20K,24K)
    unsigned int*   hh   = (unsigned int*)((char*)XS + 24576);       // 64 x 257 u32

    for (int j = t; j < EPG; j += 1024) {
        int e = g * EPG + j;
        ewL[j]  = ew[e];
        srcB[j] = (unsigned char)(ei[e] & (NPG - 1));
        dstB[j] = (unsigned char)(ei[EDG + e] & (NPG - 1));
    }
    for (int i = t; i < 64 * 257; i += 1024) hh[i] = 0;
    __syncthreads();
    if (t < 64) {                                 // pass A: per-chunk dst histogram
        int base = t * 64;
        unsigned int* hr = hh + t * 257;
        for (int i = 0; i < 64; i++) hr[dstB[base + i]]++;
    }
    __syncthreads();
    if (t < NPG) {                                // totals per dst
        int tot = 0;
        for (int c = 0; c < 64; c++) tot += hh[c * 257 + t];
        mLn[t]  = (unsigned short)tot;
        cntL[t] = (tot + 3) & ~3;
    }
    __syncthreads();
    if (t < 64) {                                 // exclusive scan, wave 0, shfl
        int carry = 0;
        if (t == 0) offL[0] = 0;
        for (int seg = 0; seg < 4; seg++) {
            int v = cntL[seg * 64 + t];
#pragma unroll
            for (int d = 1; d < 64; d <<= 1) {
                int u = __shfl_up(v, d);
                if (t >= d) v += u;
            }
            offL[seg * 64 + t + 1] = (unsigned short)(v + carry);
            carry += __shfl(v, 63);
        }
    }
    __syncthreads();
    if (t < NPG) {                                // cursors
        int run = offL[t];
        for (int c = 0; c < 64; c++) {
            int tmp = hh[c * 257 + t];
            hh[c * 257 + t] = (unsigned int)run;
            run += tmp;
        }
    }
    __syncthreads();
    if (t < 64) {                                 // pass B: stable placement (e-ascending/dst)
        int base = t * 64;
        unsigned int* hr = hh + t * 257;
        for (int i = 0; i < 64; i++) {
            int e = base + i;
            int d = dstB[e];
            int slot = hr[d];
            hr[d] = slot + 1;
            esrcL[slot] = srcB[e];
            wnL[slot]   = ewL[e];
        }
    }
    __syncthreads();
    if (t < NPG) {                                // deg -> dinv (self-loop last)
        int o = offL[t], m = mLn[t];
        float s = 0.f;
        for (int i = 0; i < m; i++) s += wnL[o + i];
        float dv = 1.0f / sqrtf(s + 1.0f);
        dinvL[t]  = dv;
        selfnL[t] = dv * dv;
    }
    __syncthreads();
    if (t < NPG) {                                // normalize + exact no-op padding
        int o = offL[t], m = mLn[t], pc = cntL[t];
        float dn = dinvL[t];
        for (int i = 0; i < m; i++)
            wnL[o + i] = dinvL[esrcL[o + i]] * wnL[o + i] * dn;
        for (int i = m; i < pc; i++) {
            esrcL[o + i] = (unsigned char)t;
            wnL[o + i]   = 0.f;
        }
    }
    __syncthreads();
    for (int i = t; i < NPG * 32; i += 1024) {    // stage X = zt[z[n]]
        int row = i >> 5, c4 = i & 31;
        int zi = z[g * NPG + row];
        XS[row * 32 + physX(row, c4)] = ((const float4*)zt)[(size_t)zi * 32 + c4];
    }
    __syncthreads();

    const unsigned int* esrcW = (const unsigned int*)esrcL;
    const float4*       wn4   = (const float4*)wnL;
    int wid  = t >> 6;
    int l    = t & 63;
    int half = l >> 5;
    int c4   = l & 31;
    int rg  = t & 31;                             // GEMM rows rg*8..+7 (r8/r12 mapping)
    int cgq = t >> 5;

    // ================= 3 GCN layers =================
#pragma unroll 1
    for (int layer = 0; layer < 3; layer++) {
        const float* W    = (layer == 0) ? W0 : (layer == 1) ? W1 : W2;
        const float* bias = (layer == 0) ? b0 : (layer == 1) ? b1 : b2;
        float* Xout       = (layer == 0) ? X0 : (layer == 1) ? X1 : nullptr;

        // ---- gather: half-wave per node, row-broadcast reads, TWO pairs in flight ----
        float4 accA[8];
#pragma unroll 1
        for (int it2 = 0; it2 < 4; it2++) {       // two node-pairs (A,B) interleaved
            int pA = wid * 8 + it2 * 2;
            int pB = pA + 1;
            int nodeA = 2 * pA + half;
            int nodeB = 2 * pB + half;
            int oA0 = offL[2 * pA], oA1 = offL[2 * pA + 1], oA2 = offL[2 * pA + 2];
            int oB1 = offL[2 * pB + 1], oB2 = offL[2 * pB + 2];
            int mA4A = (oA1 - oA0) >> 2, mA4B = (oA2 - oA1) >> 2;
            int mB4A = (oA2 - oA2) + ((oB1 - oA2) >> 2), mB4B = (oB2 - oB1) >> 2;
            int o4A = (half ? oA1 : oA0) >> 2;
            int m4A = half ? mA4B : mA4A;
            int o4B = (half ? oB1 : oA2) >> 2;
            int m4B = half ? mB4B : mB4A;
            int mmax4 = m4A > m4B ? m4A : m4B;
            unsigned int selfA = (unsigned int)nodeA * 0x01010101u;
            unsigned int selfB = (unsigned int)nodeB * 0x01010101u;
            float4 accA_ = make_float4(0.f, 0.f, 0.f, 0.f);
            float4 accB_ = make_float4(0.f, 0.f, 0.f, 0.f);

            for (int j4 = 0; j4 < mmax4; j4++) {
                // metadata for both pairs (masked -> exact no-op padding)
                bool vA = (j4 < m4A);
                bool vB = (j4 < m4B);
                int idxA = vA ? (o4A + j4) : 0;
                int idxB = vB ? (o4B + j4) : 0;
                unsigned int sA = esrcW[idxA]; float4 wA = wn4[idxA];
                unsigned int sB = esrcW[idxB]; float4 wB = wn4[idxB];
                if (!vA) { sA = selfA; wA = make_float4(0.f, 0.f, 0.f, 0.f); }
                if (!vB) { sB = selfB; wB = make_float4(0.f, 0.f, 0.f, 0.f); }
                // issue all 8 row reads back-to-back (8 outstanding LDS ops)
                int a0 =  sA        & 255, a1 = (sA >> 8)  & 255;
                int a2i = (sA >> 16) & 255, a3 = (sA >> 24) & 255;
                int b0i =  sB        & 255, b1i = (sB >> 8)  & 255;
                int b2i = (sB >> 16) & 255, b3i = (sB >> 24) & 255;
                float4 vA0 = XS[a0 * 32 + physX(a0, c4)];
                float4 vA1 = XS[a1 * 32 + physX(a1, c4)];
                float4 vA2 = XS[a2i * 32 + physX(a2i, c4)];
                float4 vA3 = XS[a3 * 32 + physX(a3, c4)];
                float4 vB0 = XS[b0i * 32 + physX(b0i, c4)];
                float4 vB1 = XS[b1i * 32 + physX(b1i, c4)];
                float4 vB2 = XS[b2i * 32 + physX(b2i, c4)];
                float4 vB3 = XS[b3i * 32 + physX(b3i, c4)];
                // FMAs, per-node chains identical to r12 (e-ascending; pads are +0.0)
                accA_.x += wA.x * vA0.x; accA_.y += wA.x * vA0.y;
                accA_.z += wA.x * vA0.z; accA_.w += wA.x * vA0.w;
                accA_.x += wA.y * vA1.x; accA_.y += wA.y * vA1.y;
                accA_.z += wA.y * vA1.z; accA_.w += wA.y * vA1.w;
                accA_.x += wA.z * vA2.x; accA_.y += wA.z * vA2.y;
                accA_.z += wA.z * vA2.z; accA_.w += wA.z * vA2.w;
                accA_.x += wA.w * vA3.x; accA_.y += wA.w * vA3.y;
                accA_.z += wA.w * vA3.z; accA_.w += wA.w * vA3.w;
                accB_.x += wB.x * vB0.x; accB_.y += wB.x * vB0.y;
                accB_.z += wB.x * vB0.z; accB_.w += wB.x * vB0.w;
                accB_.x += wB.y * vB1.x; accB_.y += wB.y * vB1.y;
                accB_.z += wB.y * vB1.z; accB_.w += wB.y * vB1.w;
                accB_.x += wB.z * vB2.x; accB_.y += wB.z * vB2.y;
                accB_.z += wB.z * vB2.z; accB_.w += wB.z * vB2.w;
                accB_.x += wB.w * vB3.x; accB_.y += wB.w * vB3.y;
                accB_.z += wB.w * vB3.z; accB_.w += wB.w * vB3.w;
            }
            {   // self-loop LAST (r12 order), both nodes
                float wsA = selfnL[nodeA];
                float4 svA = XS[nodeA * 32 + physX(nodeA, c4)];
                accA_.x += wsA * svA.x; accA_.y += wsA * svA.y;
                accA_.z += wsA * svA.z; accA_.w += wsA * svA.w;
                float wsB = selfnL[nodeB];
                float4 svB = XS[nodeB * 32 + physX(nodeB, c4)];
                accB_.x += wsB * svB.x; accB_.y += wsB * svB.y;
                accB_.z += wsB * svB.z; accB_.w += wsB * svB.w;
            }
            accA[it2 * 2]     = accA_;
            accA[it2 * 2 + 1] = accB_;
        }
        __syncthreads();
#pragma unroll
        for (int it = 0; it < 8; it++) {
            int node = 2 * (wid * 8 + it) + half;
            XS[node * 32 + physA(node, c4)] = accA[it];
        }
        __syncthreads();

        // ---- GEMM 256x128 @ 128x128: thread = 8 rows x 4 cols (r8/r12-proven) ----
        float a2[8][4];
#pragma unroll
        for (int i = 0; i < 8; i++)
#pragma unroll
            for (int j = 0; j < 4; j++) a2[i][j] = 0.f;
        for (int k4 = 0; k4 < 32; k4++) {
            float4 a4[8];
#pragma unroll
            for (int i = 0; i < 8; i++) {
                int rl = rg * 8 + i;
                a4[i] = XS[rl * 32 + physA(rl, k4)];
            }
            float4 wv[4];
#pragma unroll
            for (int kw = 0; kw < 4; kw++)
                wv[kw] = *(((const float4*)(W + (size_t)(k4 * 4 + kw) * HID)) + cgq);
#pragma unroll
            for (int kw = 0; kw < 4; kw++) {      // k strictly ascending (exact)
#pragma unroll
                for (int i = 0; i < 8; i++) {
                    float a = (kw == 0) ? a4[i].x : (kw == 1) ? a4[i].y
                            : (kw == 2) ? a4[i].z : a4[i].w;
                    a2[i][0] += a * wv[kw].x; a2[i][1] += a * wv[kw].y;
                    a2[i][2] += a * wv[kw].z; a2[i][3] += a * wv[kw].w;
                }
            }
        }
        float4 bv = ((const float4*)bias)[cgq];
        float4 oo[8];
#pragma unroll
        for (int i = 0; i < 8; i++) {
            oo[i].x = tanhf(a2[i][0] + bv.x); oo[i].y = tanhf(a2[i][1] + bv.y);
            oo[i].z = tanhf(a2[i][2] + bv.z); oo[i].w = tanhf(a2[i][3] + bv.w);
        }
        __syncthreads();
#pragma unroll
        for (int i = 0; i < 8; i++) {
            int rl = rg * 8 + i;
            XS[rl * 32 + physX(rl, cgq)] = oo[i];
        }
        __syncthreads();
        if (Xout) {                               // coalesced copy-out (X0/X1 only)
            float4* dst = (float4*)Xout + (size_t)g * NPG * 32;
            for (int i = t; i < NPG * 32; i += 1024) {
                int row = i >> 5, cc = i & 31;
                dst[i] = XS[row * 32 + physX(row, cc)];
            }
        }
    }

    // ---- layer 3 scalar: t3 = X2-row . W3 (exact 4-part structure) ----
    {
        int n = t >> 2, part = t & 3;
        const float4* w4 = (const float4*)W3;
        const float4* rb = XS + n * 32;
        float s = 0.f;
#pragma unroll
        for (int q = 0; q < 8; q++) {
            float4 v = rb[physX(n, part * 8 + q)];
            float4 ww = w4[part * 8 + q];
            s += v.x * ww.x + v.y * ww.y + v.z * ww.z + v.w * ww.w;
        }
        s += __shfl_down(s, 2, 4);
        s += __shfl_down(s, 1, 4);
        if (part == 0) t3s[n] = s;
    }
    __syncthreads();

    // ---- key + stable top-60 rank ----
    if (t < NPG) {
        int o = offL[t], m2 = mLn[t];
        float s = 0.f;
        for (int i = 0; i < m2; i++)
            s += wnL[o + i] * t3s[esrcL[o + i]];
        s += selfnL[t] * t3s[t];
        keyL[t] = tanhf(s + b3[0]);
    }
    __syncthreads();
    if (t < NPG) {
        float ki = keyL[t];
        int rank = 0;
        for (int j = 0; j < NPG; j++) {
            float kj = keyL[j];
            rank += (kj > ki) || (kj == ki && j < t);
        }
        if (rank < KTOP) selN[rank] = t;
    }
    __syncthreads();
    // ---- export: pooled X2 rows (contiguous), selected keys, selected ids ----
    if (t < KTOP) {
        int nd = selN[t];
        selI[g * KTOP + t] = nd;
        selK[g * KTOP + t] = keyL[nd];
    }
    for (int i = t; i < KTOP * 32; i += 1024) {
        int r = i >> 5, q = i & 31;
        int nd = selN[r];
        ((float4*)P2)[(size_t)g * KTOP * 32 + i] = XS[nd * 32 + physX(nd, q)];
    }
}

// ---------------- conv/MLP head: one 256-thread block per graph (r12-proven) ----------------
__global__ __launch_bounds__(256) void k_head(const float* __restrict__ X0,
                                              const float* __restrict__ X1,
                                              const float* __restrict__ P2,
                                              const float* __restrict__ selK,
                                              const int* __restrict__ selI,
                                              const float* __restrict__ c1w,
                                              const float* __restrict__ c1b,
                                              const float* __restrict__ c2w,
                                              const float* __restrict__ c2b,
                                              const float* __restrict__ l1w,
                                              const float* __restrict__ l1b,
                                              const float* __restrict__ l2w,
                                              const float* __restrict__ l2b,
                                              float* __restrict__ out) {
    __shared__ __align__(16) float pch[KTOP * 132];
    __shared__ __align__(16) float w1s[16 * 132];
    __shared__ int   seln[KTOP];
    __shared__ float selk[KTOP];
    __shared__ float c1s[16 * KTOP];
    __shared__ float mps[16 * 30];
    __shared__ float w2s[32 * 80];
    __shared__ float yb[832];
    __shared__ float l1p[256];
    __shared__ float l1v[128];

    int g = blockIdx.x, t = threadIdx.x;
    if (t < KTOP) {
        seln[t] = selI[g * KTOP + t];
        selk[t] = selK[g * KTOP + t];
    }

    float acc1[4] = {0.f, 0.f, 0.f, 0.f};
    for (int tc = 0; tc < 3; tc++) {
        const float* Xsrc = (tc == 0) ? X0 : X1;
        __syncthreads();
        for (int i = t; i < KTOP * 32; i += 256) {
            int k = i >> 5, q = i & 31;
            float4 v;
            if (tc < 2) {
                int nd = seln[k];
                v = ((const float4*)Xsrc)[((size_t)g * NPG + nd) * 32 + q];
            } else {
                v = ((const float4*)P2)[(size_t)g * KTOP * 32 + i];   // contiguous
            }
            *((float4*)&pch[k * 132 + q * 4]) = v;
        }
        for (int i = t; i < 16 * 128; i += 256) {
            int ch = i >> 7, tt = i & 127;
            w1s[ch * 132 + tt] = c1w[ch * TLDIM + tc * 128 + tt];
        }
        __syncthreads();
#pragma unroll
        for (int it = 0; it < 4; it++) {
            int e = it * 256 + t;
            if (e < 960) {                        // e = k*16 + ch
                int k = e >> 4, ch = e & 15;
                const float* pr = &pch[k * 132];
                const float* wr = &w1s[ch * 132];
                float s = 0.f;
#pragma unroll
                for (int q = 0; q < 32; q++) {
                    float4 pv = *((float4*)&pr[q * 4]);
                    float4 wv = *((float4*)&wr[q * 4]);
                    s += pv.x * wv.x + pv.y * wv.y + pv.z * wv.z + pv.w * wv.w;
                }
                acc1[it] += s;
            }
        }
    }
    __syncthreads();
#pragma unroll
    for (int it = 0; it < 4; it++) {
        int e = it * 256 + t;
        if (e < 960) {
            int k = e >> 4, ch = e & 15;
            float v = acc1[it] + selk[k] * c1w[ch * TLDIM + 384] + c1b[ch];
            c1s[ch * KTOP + k] = fmaxf(v, 0.f);
        }
    }
    for (int i = t; i < 2560; i += 256) w2s[i] = c2w[i];
    __syncthreads();
    for (int i = t; i < 480; i += 256) {
        int ch = i / 30, p = i - ch * 30;
        mps[ch * 30 + p] = fmaxf(c1s[ch * KTOP + 2 * p], c1s[ch * KTOP + 2 * p + 1]);
    }
    __syncthreads();
    for (int e = t; e < 832; e += 256) {
        int oc = e / 26, q = e - oc * 26;
        float s = 0.f;
#pragma unroll
        for (int ic = 0; ic < 16; ic++) {
            const float* mr = &mps[ic * 30 + q];
            const float* wr = &w2s[oc * 80 + ic * 5];
#pragma unroll
            for (int j = 0; j < 5; j++) s += mr[j] * wr[j];
        }
        yb[e] = fmaxf(s + c2b[oc], 0.f);
    }
    __syncthreads();
    {
        int u = t & 127, h = t >> 7;
        float s = 0.f;
        for (int d = h * 416; d < h * 416 + 416; d++) s += yb[d] * l1w[d * 128 + u];
        l1p[t] = s;
    }
    __syncthreads();
    if (t < 128) {
        float v = fmaxf(l1p[t] + l1p[t + 128] + l1b[t], 0.f);
        l1v[t] = v * l2w[t];
    }
    __syncthreads();
    if (t < 64) {
        float v = l1v[t] + l1v[t + 64];
        v += __shfl_down(v, 32);
        v += __shfl_down(v, 16);
        v += __shfl_down(v, 8);
        v += __shfl_down(v, 4);
        v += __shfl_down(v, 2);
        v += __shfl_down(v, 1);
        if (t == 0) out[g] = v + l2b[0];
    }
}

extern "C" void kernel_launch(void* const* d_in, const int* in_sizes, int n_in,
                              void* d_out, int out_size, void* d_ws, size_t ws_size,
                              hipStream_t stream) {
    (void)in_sizes; (void)n_in; (void)out_size; (void)ws_size;
    const float* zt  = (const float*)d_in[0];
    const float* W0  = (const float*)d_in[1];
    const float* b0  = (const float*)d_in[2];
    const float* W1  = (const float*)d_in[3];
    const float* b1  = (const float*)d_in[4];
    const float* W2  = (const float*)d_in[5];
    const float* b2  = (const float*)d_in[6];
    const float* W3  = (const float*)d_in[7];
    const float* b3  = (const float*)d_in[8];
    const float* c1w = (const float*)d_in[9];
    const float* c1b = (const float*)d_in[10];
    const float* c2w = (const float*)d_in[11];
    const float* c2b = (const float*)d_in[12];
    const float* l1w = (const float*)d_in[13];
    const float* l1b = (const float*)d_in[14];
    const float* l2w = (const float*)d_in[15];
    const float* l2b = (const float*)d_in[16];
    const float* ew  = (const float*)d_in[17];
    const int*   z   = (const int*)d_in[18];
    const int*   ei  = (const int*)d_in[19];
    float* out = (float*)d_out;

    char* wsp = (char*)d_ws;
    size_t off = 0;
    auto alloc = [&](size_t bytes) -> void* {
        void* p = wsp + off;
        off += (bytes + 255) & ~(size_t)255;
        return p;
    };
    float* X0   = (float*)alloc((size_t)NTOT * HID * 4);
    float* X1   = (float*)alloc((size_t)NTOT * HID * 4);
    float* P2   = (float*)alloc((size_t)BGR * KTOP * HID * 4);
    float* selK = (float*)alloc((size_t)BGR * KTOP * 4);
    int*   selI = (int*)  alloc((size_t)BGR * KTOP * 4);

    k_gnn <<<BGR, dim3(1024), 0, stream>>>(zt, z, ei, ew,
                                           W0, b0, W1, b1, W2, b2, W3, b3,
                                           X0, X1, P2, selK, selI);
    k_head<<<BGR, dim3(256), 0, stream>>>(X0, X1, P2, selK, selI,
                                          c1w, c1b, c2w, c2b,
                                          l1w, l1b, l2w, l2b, out);
}